// Round 15
// baseline (33.608 us; speedup 1.0000x reference)
//
#include <hip/hip_runtime.h>

// MTRNN single step. Live computation after DCE (reference returns only y):
//   io_new = tanh([x|io|cf] @ (0.5*[Wi2io | Wio2io+I | Wcf2io])^T + bsum)
//   y      = tanh(io_new @ Wio2o^T + bio2o)
// cf_new / cs_new dead. bf16 MFMA, f32 accumulate.
// r15 = r14's counted-vmcnt 2-buffer staging at BN=256 (A refetch 4x -> 2x):
//  gemm1: BM=64 BN=256 BK=64, 512 thr, grid 256, WAITB(6)+BARL. 151 MB staged
//         (-33% vs r8's 226 MB).
//  gemm2: BM=32 BN=64, 128 thr, grid 512, 3-buffer counted (WAITB(6)). [r14]

typedef float f32x4 __attribute__((ext_vector_type(4)));
typedef __bf16 bf16x4 __attribute__((ext_vector_type(4)));
typedef __bf16 bf16x8 __attribute__((ext_vector_type(8)));
typedef unsigned short u16x4 __attribute__((ext_vector_type(4)));

__device__ __forceinline__ unsigned short f2bf(float f) {
    unsigned u = __builtin_bit_cast(unsigned, f);
    u += 0x7FFFu + ((u >> 16) & 1u);
    return (unsigned short)(u >> 16);
}

__device__ __forceinline__ float tanh_fast(float x) {
    float e = __expf(2.0f * x);
    return 1.0f - 2.0f * __builtin_amdgcn_rcpf(e + 1.0f);
}

// async global->LDS, 16B per lane. LDS dest is wave-uniform base + lane*16.
__device__ __forceinline__ void gload16(const void* g, void* l) {
    __builtin_amdgcn_global_load_lds(
        (const __attribute__((address_space(1))) void*)g,
        (__attribute__((address_space(3))) void*)l, 16, 0, 0);
}

// counted wait + barrier: keep newer stages' loads in flight across it.
#define WAITB(N) asm volatile("s_waitcnt vmcnt(" #N ")\n\ts_barrier" ::: "memory")
// plain barrier (guards LDS overwrite after all waves finished reading).
#define BARL()   asm volatile("s_waitcnt lgkmcnt(0)\n\ts_barrier" ::: "memory")

// ---------------------------------------------------------------------------
// Kernel 0: pack weights to bf16, CHUNK-XOR swizzled per 64-col K-tile:
// element (n,k) -> n*L + (k&~63) + ((((k>>3)&7) ^ (n&7))<<3) + (k&7).
//   wcat[512][1152] = 0.5*[Wi2io | Wio2io + I | Wcf2io]
//   w2s [128][512]  = Wio2o
//   bsum[512]       = 0.5*(bi2io + bio2io + bcf2io)
// ---------------------------------------------------------------------------
__global__ __launch_bounds__(256) void k_convert(
    const float* __restrict__ Wi2io, const float* __restrict__ Wio2io,
    const float* __restrict__ Wcf2io, const float* __restrict__ Wio2o,
    const float* __restrict__ b1, const float* __restrict__ b2,
    const float* __restrict__ b3,
    unsigned short* __restrict__ wcat, unsigned short* __restrict__ w2s,
    float* __restrict__ bsum)
{
    int idx = blockIdx.x * 256 + threadIdx.x;
    if (idx < 147456) {              // 512*1152/4 quads
        int n = idx / 288;
        int k = (idx - n * 288) * 4;
        const float* s;
        if (k < 128)      s = Wi2io  + n * 128 + k;
        else if (k < 640) s = Wio2io + n * 512 + (k - 128);
        else              s = Wcf2io + n * 512 + (k - 640);
        f32x4 v = *(const f32x4*)s;
        u16x4 h;
        #pragma unroll
        for (int t = 0; t < 4; ++t) {
            float f = 0.5f * v[t];
            int kk = k + t;
            if (kk >= 128 && kk < 640 && (kk - 128) == n) f += 0.5f;  // +0.5*I
            h[t] = f2bf(f);
        }
        int ad = n * 1152 + (k & ~63) + ((((k >> 3) & 7) ^ (n & 7)) << 3) + (k & 7);
        *(u16x4*)(wcat + ad) = h;
    } else if (idx < 163840) {       // 128*512/4 quads
        int q = idx - 147456;
        int n = q >> 7;
        int k = (q & 127) * 4;
        f32x4 v = *(const f32x4*)(Wio2o + n * 512 + k);
        u16x4 h; h[0]=f2bf(v[0]); h[1]=f2bf(v[1]); h[2]=f2bf(v[2]); h[3]=f2bf(v[3]);
        int ad = n * 512 + (k & ~63) + ((((k >> 3) & 7) ^ (n & 7)) << 3) + (k & 7);
        *(u16x4*)(w2s + ad) = h;
    } else if (idx < 164352) {
        int n = idx - 163840;
        bsum[n] = 0.5f * (b1[n] + b2[n] + b3[n]);
    }
}

// ---------------------------------------------------------------------------
// Kernel 1: ionew = tanh(Acat @ wcat^T + bsum), bf16 out (stored swizzled).
// M=8192 N=512 K=1152. BM=64 BN=256 BK=64, 512 thr (8 waves 2m x 4n, wave
// 32x64). Grid 256 = 1 block/CU. LDS 2 x (A f32 16KB | B bf16 32KB) = 96KB.
// 2-buffer counted pipeline: WAITB(6) retires tile t while t+1's 6 loads fly;
// BARL guards the buffer overwrite. XCD-affine: 16 panels x 2 colb per XCD.
// Staged traffic: A 2x37.7=75.5 MB + B 128x0.59=75.5 MB (-33% vs r8).
// ---------------------------------------------------------------------------
__global__ __launch_bounds__(512) void k_gemm1(
    const float* __restrict__ x, const float* __restrict__ io,
    const float* __restrict__ cf,
    const unsigned short* __restrict__ wcat,
    const float* __restrict__ bsum,
    unsigned short* __restrict__ ionew)
{
    __shared__ __align__(16) char lds[2][49152];   // A @0 (16KB), B @16384 (32KB)

    const int tid = threadIdx.x, b = blockIdx.x;
    const int xcd = b & 7, idx = b >> 3;            // idx 0..31
    const int m0 = ((xcd << 4) | (idx & 15)) << 6;  // panel*64
    const int n0 = (idx >> 4) << 8;                 // colb*256

    const int lane = tid & 63, wid = tid >> 6;
    const int li = lane & 15, lh = lane >> 4;
    const int wm = (wid >> 2) << 5;       // 0/32
    const int wn = (wid & 3) << 6;        // 0/64/128/192

    // A staging: 64 rows x 16 f32-chunks (swizzle in source offset).
    // wave w covers rows [8w, 8w+8) in 2 issues of 4 rows.
    int a_off_x[2], a_off_s[2];
    #pragma unroll
    for (int j = 0; j < 2; ++j) {
        int r = (wid << 3) + (j << 2) + (lane >> 4);     // A row 0..63
        int cs = (lane & 15) ^ (r & 15);                 // swizzled 16B chunk
        a_off_x[j] = (m0 + r) * 128 + cs * 4;
        a_off_s[j] = (m0 + r) * 512 + cs * 4;
    }
    // B staging: 256 rows x 8 chunks; wave w covers rows [32w, 32w+32).
    int b_off[4];
    #pragma unroll
    for (int j = 0; j < 4; ++j) {
        int rb = (wid << 5) + (j << 3) + (lane >> 3);    // B row 0..255
        b_off[j] = (n0 + rb) * 1152 + ((lane & 7) << 3); // linear (pre-swz)
    }
    const int adstA = wid << 11;   // + j<<10 (A region: 2KB/wave)
    const int adstB = wid << 12;   // + j<<10 (B region: 4KB/wave)

    f32x4 zz = {0.f, 0.f, 0.f, 0.f};
    f32x4 acc[2][4];
    #pragma unroll
    for (int i = 0; i < 2; ++i)
        #pragma unroll
        for (int j = 0; j < 4; ++j) acc[i][j] = zz;

#define STAGE1(KT, BUF) do {                                                   \
        int K_ = (KT);                                                         \
        char* A_ = (BUF); char* B_ = (BUF) + 16384;                            \
        if (K_ < 2) {                                                          \
            const float* sp = x + (K_ << 6);                                   \
            _Pragma("unroll")                                                  \
            for (int j = 0; j < 2; ++j)                                        \
                gload16(sp + a_off_x[j], A_ + adstA + (j << 10));              \
        } else if (K_ < 10) {                                                  \
            const float* sp = io + ((K_ - 2) << 6);                            \
            _Pragma("unroll")                                                  \
            for (int j = 0; j < 2; ++j)                                        \
                gload16(sp + a_off_s[j], A_ + adstA + (j << 10));              \
        } else {                                                               \
            const float* sp = cf + ((K_ - 10) << 6);                           \
            _Pragma("unroll")                                                  \
            for (int j = 0; j < 2; ++j)                                        \
                gload16(sp + a_off_s[j], A_ + adstA + (j << 10));              \
        }                                                                      \
        const unsigned short* wp = wcat + (K_ << 6);                           \
        _Pragma("unroll")                                                      \
        for (int j = 0; j < 4; ++j)                                            \
            gload16(wp + b_off[j], B_ + adstB + (j << 10));                    \
    } while (0)

#define COMPUTE1(BUF) do {                                                     \
        const char* A_ = (BUF); const char* B_ = (BUF) + 16384;                \
        _Pragma("unroll")                                                      \
        for (int ks = 0; ks < 2; ++ks) {                                       \
            bf16x8 af[2];                                                      \
            _Pragma("unroll")                                                  \
            for (int mi = 0; mi < 2; ++mi) {                                   \
                int r = wm + mi * 16 + li;                                     \
                int c0 = ks * 8 + lh * 2;                                      \
                f32x4 a0 = *(const f32x4*)(A_ + r * 256 +                      \
                                           ((c0 ^ (r & 15)) << 4));            \
                f32x4 a1 = *(const f32x4*)(A_ + r * 256 +                      \
                                           (((c0 + 1) ^ (r & 15)) << 4));      \
                bf16x4 h0 = __builtin_convertvector(a0, bf16x4);               \
                bf16x4 h1 = __builtin_convertvector(a1, bf16x4);               \
                af[mi] = __builtin_shufflevector(h0, h1, 0,1,2,3,4,5,6,7);     \
            }                                                                  \
            int c = ks * 4 + lh;                                               \
            _Pragma("unroll")                                                  \
            for (int nj = 0; nj < 4; ++nj) {                                   \
                int rb = wn + nj * 16 + li;                                    \
                bf16x8 bv = *(const bf16x8*)(B_ + rb * 128 +                   \
                                             ((c ^ (rb & 7)) << 4));           \
                acc[0][nj] = __builtin_amdgcn_mfma_f32_16x16x32_bf16(          \
                    af[0], bv, acc[0][nj], 0, 0, 0);                           \
                acc[1][nj] = __builtin_amdgcn_mfma_f32_16x16x32_bf16(          \
                    af[1], bv, acc[1][nj], 0, 0, 0);                           \
            }                                                                  \
        }                                                                      \
    } while (0)

    STAGE1(0, lds[0]);
    STAGE1(1, lds[1]);
    #pragma unroll 1
    for (int t = 0; t < 18; ++t) {
        if (t < 17) { WAITB(6); } else { WAITB(0); }   // tile t retired
        char* cb = lds[t & 1];
        COMPUTE1(cb);
        if (t + 2 < 18) {
            BARL();                                    // all reads of cb done
            STAGE1(t + 2, cb);
        }
    }
#undef STAGE1
#undef COMPUTE1

    // epilogue: bias+tanh, store bf16 chunk-swizzled (gemm2-ready layout)
    #pragma unroll
    for (int nj = 0; nj < 4; ++nj) {
        int gn = n0 + wn + nj * 16 + li;
        float bb = bsum[gn];
        #pragma unroll
        for (int mi = 0; mi < 2; ++mi) {
            #pragma unroll
            for (int r = 0; r < 4; ++r) {
                int gm = m0 + wm + mi * 16 + (lh << 2) + r;
                float v = tanh_fast(acc[mi][nj][r] + bb);
                int ad = gm * 512 + (gn & ~63) +
                         ((((gn >> 3) & 7) ^ (gm & 7)) << 3) + (gn & 7);
                ionew[ad] = f2bf(v);
            }
        }
    }
}

// ---------------------------------------------------------------------------
// Kernel 2: y = tanh(ionew @ w2s^T + bio2o). M=8192 N=128 K=512.
// BM=32 BN=64 BK=64, 128 thr (2 waves, wave 32x32). Grid 512 = 2+ blocks/CU.
// 3-buffer counted pipeline (6 gl_lds/wave/stage -> WAITB(6)). [r14 verbatim]
// ---------------------------------------------------------------------------
__global__ __launch_bounds__(128, 2) void k_gemm2(
    const unsigned short* __restrict__ ionew,
    const unsigned short* __restrict__ w2s,
    const float* __restrict__ b4,
    float* __restrict__ out)
{
    __shared__ __align__(16) char lds[3][12288];   // A @0 (4KB), B @4096 (8KB)

    const int tid = threadIdx.x, b = blockIdx.x;
    const int xcd = b & 7, q = b >> 3;             // q 0..63
    const int m0 = ((xcd << 5) | (q & 31)) << 5;   // rows match writer XCD
    const int n0 = (q >> 5) << 6;                  // 0 / 64

    const int lane = tid & 63, wid = tid >> 6;     // wid 0..1
    const int li = lane & 15, lh = lane >> 4;

    // A: 32 rows x 8 chunks; B: 64 rows x 8 chunks (both pre-swizzled global)
    int a_off[2], b_off[4];
    #pragma unroll
    for (int j = 0; j < 2; ++j) {
        int r = (wid << 4) + (j << 3) + (lane >> 3);      // A row 0..31
        a_off[j] = (m0 + r) * 512 + ((lane & 7) << 3);
    }
    #pragma unroll
    for (int j = 0; j < 4; ++j) {
        int r = (wid << 5) + (j << 3) + (lane >> 3);      // B row 0..63
        b_off[j] = (n0 + r) * 512 + ((lane & 7) << 3);
    }

    f32x4 zz = {0.f, 0.f, 0.f, 0.f};
    f32x4 acc[2][2];
    acc[0][0] = zz; acc[0][1] = zz; acc[1][0] = zz; acc[1][1] = zz;

#define STAGE2(KT, BUF) do {                                                   \
        int K_ = (KT);                                                         \
        char* A_ = (BUF); char* B_ = (BUF) + 4096;                             \
        _Pragma("unroll")                                                      \
        for (int j = 0; j < 2; ++j)                                            \
            gload16(ionew + a_off[j] + (K_ << 6),                              \
                    A_ + (wid << 11) + (j << 10));                             \
        _Pragma("unroll")                                                      \
        for (int j = 0; j < 4; ++j)                                            \
            gload16(w2s + b_off[j] + (K_ << 6),                                \
                    B_ + (wid << 12) + (j << 10));                             \
    } while (0)

#define COMPUTE2(BUF) do {                                                     \
        const char* A_ = (BUF); const char* B_ = (BUF) + 4096;                 \
        _Pragma("unroll")                                                      \
        for (int ks = 0; ks < 2; ++ks) {                                       \
            int c = ks * 4 + lh;                                               \
            bf16x8 av[2];                                                      \
            _Pragma("unroll")                                                  \
            for (int mi = 0; mi < 2; ++mi) {                                   \
                int r = mi * 16 + li;                                          \
                av[mi] = *(const bf16x8*)(A_ + r * 128 + ((c ^ (r & 7)) << 4));\
            }                                                                  \
            _Pragma("unroll")                                                  \
            for (int nj = 0; nj < 2; ++nj) {                                   \
                int rb = (wid << 5) + nj * 16 + li;                            \
                bf16x8 bv = *(const bf16x8*)(B_ + rb * 128 +                   \
                                             ((c ^ (rb & 7)) << 4));           \
                acc[0][nj] = __builtin_amdgcn_mfma_f32_16x16x32_bf16(          \
                    av[0], bv, acc[0][nj], 0, 0, 0);                           \
                acc[1][nj] = __builtin_amdgcn_mfma_f32_16x16x32_bf16(          \
                    av[1], bv, acc[1][nj], 0, 0, 0);                           \
            }                                                                  \
        }                                                                      \
    } while (0)

    STAGE2(0, lds[0]);
    STAGE2(1, lds[1]);
    char* p0 = lds[0]; char* p1 = lds[1]; char* p2 = lds[2];
    #pragma unroll 1
    for (int t = 0; t < 7; ++t) {
        WAITB(6);
        if (t + 2 < 8) STAGE2(t + 2, p2);
        COMPUTE2(p0);
        char* tmp = p0; p0 = p1; p1 = p2; p2 = tmp;
    }
    WAITB(0);
    COMPUTE2(p0);                          // tile 7
#undef STAGE2
#undef COMPUTE2

    #pragma unroll
    for (int nj = 0; nj < 2; ++nj) {
        int n = n0 + (wid << 5) + nj * 16 + li;
        float bb = b4[n];
        #pragma unroll
        for (int mi = 0; mi < 2; ++mi) {
            #pragma unroll
            for (int r = 0; r < 4; ++r) {
                int gm = m0 + mi * 16 + (lh << 2) + r;
                out[(size_t)gm * 128 + n] = tanh_fast(acc[mi][nj][r] + bb);
            }
        }
    }
}

// ---------------------------------------------------------------------------
extern "C" void kernel_launch(void* const* d_in, const int* in_sizes, int n_in,
                              void* d_out, int out_size, void* d_ws, size_t ws_size,
                              hipStream_t stream)
{
    const float* x      = (const float*)d_in[0];
    const float* io     = (const float*)d_in[1];
    const float* cf     = (const float*)d_in[2];
    // d_in[3] cs_state: dead (does not feed y)
    const float* Wi2io  = (const float*)d_in[4];
    const float* bi2io  = (const float*)d_in[5];
    const float* Wio2o  = (const float*)d_in[6];
    const float* bio2o  = (const float*)d_in[7];
    const float* Wio2io = (const float*)d_in[8];
    const float* bio2io = (const float*)d_in[9];
    const float* Wcf2io = (const float*)d_in[12];
    const float* bcf2io = (const float*)d_in[13];
    float* out = (float*)d_out;

    // ws: wcat 1,179,648 | w2s 131,072 | bsum 2,048 | ionew 8,388,608
    char* ws = (char*)d_ws;
    unsigned short* wcat  = (unsigned short*)ws;
    unsigned short* w2s   = (unsigned short*)(ws + 1179648);
    float*          bsum  = (float*)(ws + 1310720);
    unsigned short* ionew = (unsigned short*)(ws + 1312768);

    hipLaunchKernelGGL(k_convert, dim3(642), dim3(256), 0, stream,
                       Wi2io, Wio2io, Wcf2io, Wio2o, bi2io, bio2io, bcf2io,
                       wcat, w2s, bsum);
    hipLaunchKernelGGL(k_gemm1, dim3(256), dim3(512), 0, stream,
                       x, io, cf, wcat, bsum, ionew);
    hipLaunchKernelGGL(k_gemm2, dim3(512), dim3(128), 0, stream,
                       ionew, w2s, bio2o, out);
}